// Round 6
// baseline (5784.690 us; speedup 1.0000x reference)
//
#include <hip/hip_runtime.h>

// GraphProcessor: 2-layer hetero GNN (TransformerConv + GATConv + EdgeConv)
// Round 14: r13 + software-pipelined W1 staging (T14 async-STAGE split).
//   r13 residual: per-nc serial chain exposed ~250cyc L2 latency in the W1
//   stage (drained before the barrier) + bias loads trapped behind the
//   lgkmcnt fence. Now slice nc+1 is prefetched into 8 uint4 REGISTERS while
//   nc computes; the barrier section is just 8 ds_writes. b1 bias loads are
//   hoisted above stage-1 so they land during the MFMAs.
//   MFMA accumulation order unchanged -> bit-identical output (absmax canary
//   0.265625).

typedef unsigned int u32;
typedef unsigned short u16;

#define NL 50000
#define NP 100000
#define ELL 500000
#define EPPE 400000
#define ELPE 500000
#define EPLE 500000
#define ENC_NEG_INF 0x007FFFFFu

using bf16x8 = __attribute__((ext_vector_type(8))) short;
using f32x4  = __attribute__((ext_vector_type(4))) float;
using u16x4  = __attribute__((ext_vector_type(4))) unsigned short;

__device__ __forceinline__ float bf2f(u16 h) { return __uint_as_float(((u32)h) << 16); }
__device__ __forceinline__ u16 f2bf(float f) {
    u32 u = __float_as_uint(f);
    u += 0x7FFFu + ((u >> 16) & 1u);   // round-to-nearest-even
    return (u16)(u >> 16);
}
// order-preserving float<->uint encoding (for atomicMax on floats)
__device__ __forceinline__ u32 encf(float f) {
    u32 u = __float_as_uint(f);
    return (u & 0x80000000u) ? ~u : (u | 0x80000000u);
}
__device__ __forceinline__ float decf(u32 u) {
    return __uint_as_float((u & 0x80000000u) ? (u ^ 0x80000000u) : ~u);
}

// ---------------- dtype detection ----------------
__global__ void k_detect(const u32* __restrict__ x, u32* __restrict__ flag) {
    int lane = threadIdx.x;   // 64 threads
    u16 lo = (u16)(x[lane] & 0xFFFFu);
    float a = fabsf(bf2f(lo));
    int inband = (a > 1e-4f && a < 100.f) ? 1 : 0;
    unsigned long long m = __ballot(inband);
    if (lane == 0) flag[0] = (__popcll(m) >= 32) ? 1u : 0u;   // 1 = bf16 inputs
}

// ---------------- elementwise / utility kernels ----------------

__global__ __launch_bounds__(256) void k_cast_any(const void* __restrict__ in,
                                                  float* __restrict__ out, int n,
                                                  const u32* __restrict__ flag) {
    int i = blockIdx.x * 256 + threadIdx.x;
    if (i >= n) return;
    if (flag[0]) out[i] = bf2f(((const u16*)in)[i]);
    else         out[i] = ((const float*)in)[i];
}

__global__ __launch_bounds__(256) void k_store_out(const float* __restrict__ in,
                                                   void* __restrict__ out, size_t off, int n,
                                                   const u32* __restrict__ flag) {
    int i = blockIdx.x * 256 + threadIdx.x;
    if (i >= n) return;
    if (flag[0]) ((u16*)out)[off + i] = f2bf(in[i]);
    else         ((float*)out)[off + i] = in[i];
}

__global__ __launch_bounds__(256) void k_fill_u32(u32* __restrict__ p, u32 v, int n) {
    int i = blockIdx.x * 256 + threadIdx.x;
    if (i < n) p[i] = v;
}

__global__ void k_add128(const float* __restrict__ a, const float* __restrict__ b,
                         float* __restrict__ o) {
    int t = threadIdx.x;
    o[t] = a[t] + b[t];
}

// transpose+cast: in = nconv blocks of [K][N] f32; out = nconv blocks of [N][K] bf16
__global__ __launch_bounds__(256) void k_tcast(const float* __restrict__ in,
                                               u16* __restrict__ out,
                                               int K, int N, int total) {
    int i = blockIdx.x * 256 + threadIdx.x;
    if (i >= total) return;
    int per = K * N;
    int c = i / per, r = i - c * per;
    int k = r / N, n = r - k * N;
    out[(size_t)c * per + (size_t)n * K + k] = f2bf(in[i]);
}

// fold EdgeConv's "xj - xi" into W1: rows 0..127 -= rows 128..255 (per conv)
__global__ __launch_bounds__(256) void k_w1mod(float* __restrict__ w, int total) {
    int i = blockIdx.x * 256 + threadIdx.x;   // total = 4 * 128 * 512
    if (i >= total) return;
    int c = i >> 16;              // / (128*512)
    int r = (i >> 9) & 127;
    int col = i & 511;
    float* base = w + c * 131072;
    base[r * 512 + col] -= base[(r + 128) * 512 + col];
}

// split f32 -> bf16 hi/lo planes (4 elems/thread)
__global__ __launch_bounds__(256) void k_split(const float4* __restrict__ x,
                                               u16x4* __restrict__ xh,
                                               u16x4* __restrict__ xl, int n4) {
    int i = blockIdx.x * 256 + threadIdx.x;
    if (i >= n4) return;
    float4 f = x[i];
    float fv[4] = {f.x, f.y, f.z, f.w};
    u16x4 h, l;
#pragma unroll
    for (int j = 0; j < 4; ++j) {
        u16 hi = f2bf(fv[j]);
        h[j] = hi;
        l[j] = f2bf(fv[j] - bf2f(hi));
    }
    xh[i] = h; xl[i] = l;
}

// o[b*128+k] = sum_i W[k*128+i] * a_b[i]  for b in {0,1}  (<<<2,128>>>)
__global__ void k_matvec2(const float* __restrict__ W, const float* __restrict__ a0,
                          const float* __restrict__ a1, float* __restrict__ o) {
    __shared__ float as[128];
    const float* a = blockIdx.x ? a1 : a0;
    int t = threadIdx.x;
    as[t] = a[t];
    __syncthreads();
    float s = 0.f;
#pragma unroll 8
    for (int i = 0; i < 128; ++i) s += W[t * 128 + i] * as[i];
    o[blockIdx.x * 128 + t] = s;
}

// s[n] = X[n,:] . wv   (one wave per node)
__global__ __launch_bounds__(256) void k_node_scalar(const float* __restrict__ X,
                                                     const float* __restrict__ wv,
                                                     float* __restrict__ s, int n) {
    int wid = (blockIdx.x * 256 + threadIdx.x) >> 6;
    int lane = threadIdx.x & 63;
    if (wid >= n) return;
    const float* xr = X + (size_t)wid * 128;
    float v = xr[lane] * wv[lane] + xr[lane + 64] * wv[lane + 64];
#pragma unroll
    for (int o = 32; o; o >>= 1) v += __shfl_xor(v, o);
    if (lane == 0) s[wid] = v;
}

// ---------------- CSR build: count -> scan -> scatter ----------------

__global__ __launch_bounds__(256) void k_deg(const int* __restrict__ dst,
                                             int* __restrict__ deg, int E) {
    int i = blockIdx.x * 256 + threadIdx.x;
    if (i < E) atomicAdd(deg + dst[i], 1);
}

__global__ __launch_bounds__(256) void k_scan1(const int* __restrict__ deg,
                                               int* __restrict__ rp,
                                               int* __restrict__ aux, int n) {
    __shared__ int ls[256];
    int t = threadIdx.x;
    int i = blockIdx.x * 256 + t;
    int v = (i < n) ? deg[i] : 0;
    ls[t] = v;
    __syncthreads();
#pragma unroll
    for (int off = 1; off < 256; off <<= 1) {
        int a = (t >= off) ? ls[t - off] : 0;
        __syncthreads();
        ls[t] += a;
        __syncthreads();
    }
    if (i < n) rp[i] = ls[t] - v;   // exclusive
    if (t == 255) aux[blockIdx.x] = ls[255];
}

__global__ __launch_bounds__(512) void k_scan2(int* __restrict__ aux, int nb) {
    __shared__ int ls[512];
    int t = threadIdx.x;
    int v = (t < nb) ? aux[t] : 0;
    ls[t] = v;
    __syncthreads();
#pragma unroll
    for (int off = 1; off < 512; off <<= 1) {
        int a = (t >= off) ? ls[t - off] : 0;
        __syncthreads();
        ls[t] += a;
        __syncthreads();
    }
    if (t < nb) aux[t] = ls[t] - v;   // exclusive
}

__global__ __launch_bounds__(256) void k_scan3(int* __restrict__ rp,
                                               const int* __restrict__ aux,
                                               int n, int E) {
    int i = blockIdx.x * 256 + threadIdx.x;
    if (i > n) return;
    if (i == n) rp[n] = E;
    else        rp[i] += aux[i >> 8];
}

__global__ __launch_bounds__(256) void k_copy_i32(const int* __restrict__ a,
                                                  int* __restrict__ b, int n) {
    int i = blockIdx.x * 256 + threadIdx.x;
    if (i < n) b[i] = a[i];
}

__global__ __launch_bounds__(256) void k_scat(const int* __restrict__ src,
                                              const int* __restrict__ dst,
                                              int* __restrict__ cur,
                                              int* __restrict__ col, int E) {
    int i = blockIdx.x * 256 + threadIdx.x;
    if (i >= E) return;
    int pos = atomicAdd(cur + dst[i], 1);
    col[pos] = src[i];
}

// ---------------- fused attention (one wave per dst row) ----------------

__global__ __launch_bounds__(256) void k_attn_trans(const float* __restrict__ Tq,
                                                    const float* __restrict__ Tk,
                                                    const float* __restrict__ Tv,
                                                    const int* __restrict__ rp,
                                                    const int* __restrict__ col,
                                                    float* __restrict__ out, int nd) {
    int row = (blockIdx.x * 256 + threadIdx.x) >> 6;
    int lane = threadIdx.x & 63;
    if (row >= nd) return;
    int e0 = rp[row], e1 = rp[row + 1];
    if (e0 >= e1) return;                      // no edges: out keeps skip
    const float* q = Tq + (size_t)row * 128;
    float q0 = q[lane], q1 = q[lane + 64];
    float m = -3.0e38f, l = 0.f, o0 = 0.f, o1 = 0.f;
    for (int e = e0; e < e1; ++e) {
        int s = col[e];
        const float* kr = Tk + (size_t)s * 128;
        float d = q0 * kr[lane] + q1 * kr[lane + 64];
#pragma unroll
        for (int off = 32; off; off >>= 1) d += __shfl_xor(d, off);
        d *= 0.08838834764831845f;             // 1/sqrt(128)
        float mn = fmaxf(m, d);
        float al = expf(m - mn);               // first iter: exp(-inf)=0
        float p  = expf(d - mn);
        const float* vr = Tv + (size_t)s * 128;
        l  = l * al + p;
        o0 = o0 * al + p * vr[lane];
        o1 = o1 * al + p * vr[lane + 64];
        m = mn;
    }
    float inv = 1.f / (l + 1e-16f);
    size_t base = (size_t)row * 128;
    out[base + lane]      += o0 * inv;
    out[base + lane + 64] += o1 * inv;
}

__global__ __launch_bounds__(256) void k_attn_gat(const float* __restrict__ hs,
                                                  const float* __restrict__ ss,
                                                  const float* __restrict__ sd,
                                                  const int* __restrict__ rp,
                                                  const int* __restrict__ col,
                                                  float* __restrict__ out, int nd) {
    int row = (blockIdx.x * 256 + threadIdx.x) >> 6;
    int lane = threadIdx.x & 63;
    if (row >= nd) return;
    int e0 = rp[row], e1 = rp[row + 1];
    if (e0 >= e1) return;
    float sdv = sd[row];
    float m = -3.0e38f, l = 0.f, o0 = 0.f, o1 = 0.f;
    for (int e = e0; e < e1; ++e) {
        int s = col[e];
        float sc = ss[s] + sdv;
        sc = sc > 0.f ? sc : 0.2f * sc;
        float mn = fmaxf(m, sc);
        float al = expf(m - mn);
        float p  = expf(sc - mn);
        const float* hr = hs + (size_t)s * 128;
        l  = l * al + p;
        o0 = o0 * al + p * hr[lane];
        o1 = o1 * al + p * hr[lane + 64];
        m = mn;
    }
    float inv = 1.f / (l + 1e-16f);
    size_t base = (size_t)row * 128;
    out[base + lane]      += o0 * inv;
    out[base + lane + 64] += o1 * inv;
}

// ---------------- MFMA GEMM (node-level): C = A[MxK] @ Wt^T + bias ----------------
// Wt bf16 [N][K]. A f32 staged as hi/lo bf16 planes (2-pass MFMA, ~f32 precision).
// Tile 128x128, BK=32, 4 waves (each 64x64 quadrant, 4x4 frags).
#define LSTR 40   // LDS row stride in bf16 (32 + 8 pad)

__global__ __launch_bounds__(256) void k_mgemm(const float* __restrict__ A_,
                                               const u16* __restrict__ Wt,
                                               const float* __restrict__ bias,
                                               float* __restrict__ Cout,
                                               int M, int N, int K) {
    __shared__ u16 Ahs[128 * LSTR];
    __shared__ u16 Als[128 * LSTR];
    __shared__ u16 Bss[128 * LSTR];
    const int tid = threadIdx.x;
    const int m0 = blockIdx.y * 128, n0 = blockIdx.x * 128;

    const int srow = tid >> 1, sseg = (tid & 1) * 16;
    int arow = m0 + srow;
    if (arow >= M) arow = M - 1;          // duplicate row; stores guarded
    const float* Af = A_ + (size_t)arow * K + sseg;
    u16* AhW = &Ahs[srow * LSTR + sseg];
    u16* AlW = &Als[srow * LSTR + sseg];
    const u16* Bp = Wt + (size_t)(n0 + srow) * K + sseg;
    u16* BsW = &Bss[srow * LSTR + sseg];

    const int lane = tid & 63, wv = tid >> 6;
    const int mw = (wv >> 1) * 64, nw = (wv & 1) * 64;
    const int fm = lane & 15, fq = lane >> 4;
    const u16* aRh = &Ahs[(mw + fm) * LSTR + fq * 8];
    const u16* aRl = &Als[(mw + fm) * LSTR + fq * 8];
    const u16* bR  = &Bss[(nw + fm) * LSTR + fq * 8];

    f32x4 acc[4][4];
#pragma unroll
    for (int i = 0; i < 4; ++i)
#pragma unroll
        for (int j = 0; j < 4; ++j) { acc[i][j][0]=0.f; acc[i][j][1]=0.f; acc[i][j][2]=0.f; acc[i][j][3]=0.f; }

    for (int k0 = 0; k0 < K; k0 += 32) {
        __syncthreads();
        float4 f0 = *(const float4*)(Af + k0);
        float4 f1 = *(const float4*)(Af + k0 + 4);
        float4 f2 = *(const float4*)(Af + k0 + 8);
        float4 f3 = *(const float4*)(Af + k0 + 12);
        float v[16] = {f0.x,f0.y,f0.z,f0.w, f1.x,f1.y,f1.z,f1.w,
                       f2.x,f2.y,f2.z,f2.w, f3.x,f3.y,f3.z,f3.w};
        u32 hp[8], lp[8];
#pragma unroll
        for (int i = 0; i < 8; ++i) {
            float x0 = v[2 * i], x1 = v[2 * i + 1];
            u16 h0 = f2bf(x0), h1 = f2bf(x1);
            u16 l0 = f2bf(x0 - bf2f(h0)), l1 = f2bf(x1 - bf2f(h1));
            hp[i] = (u32)h0 | ((u32)h1 << 16);
            lp[i] = (u32)l0 | ((u32)l1 << 16);
        }
        uint4 h04 = {hp[0], hp[1], hp[2], hp[3]}, h48 = {hp[4], hp[5], hp[6], hp[7]};
        uint4 l04 = {lp[0], lp[1], lp[2], lp[3]}, l48 = {lp[4], lp[5], lp[6], lp[7]};
        *(uint4*)AhW = h04; *(uint4*)(AhW + 8) = h48;
        *(uint4*)AlW = l04; *(uint4*)(AlW + 8) = l48;
        *(uint4*)BsW       = *(const uint4*)(Bp + k0);
        *(uint4*)(BsW + 8) = *(const uint4*)(Bp + k0 + 8);
        __syncthreads();

        bf16x8 ah[4], al[4], bfr[4];
#pragma unroll
        for (int i = 0; i < 4; ++i) ah[i]  = *(const bf16x8*)(aRh + i * 16 * LSTR);
#pragma unroll
        for (int i = 0; i < 4; ++i) al[i]  = *(const bf16x8*)(aRl + i * 16 * LSTR);
#pragma unroll
        for (int j = 0; j < 4; ++j) bfr[j] = *(const bf16x8*)(bR + j * 16 * LSTR);
#pragma unroll
        for (int i = 0; i < 4; ++i)
#pragma unroll
            for (int j = 0; j < 4; ++j) {
                acc[i][j] = __builtin_amdgcn_mfma_f32_16x16x32_bf16(ah[i], bfr[j],
                                                                    acc[i][j], 0, 0, 0);
                acc[i][j] = __builtin_amdgcn_mfma_f32_16x16x32_bf16(al[i], bfr[j],
                                                                    acc[i][j], 0, 0, 0);
            }
    }

    float bb[4];
#pragma unroll
    for (int j = 0; j < 4; ++j)
        bb[j] = bias ? bias[n0 + nw + j * 16 + fm] : 0.f;
#pragma unroll
    for (int i = 0; i < 4; ++i) {
#pragma unroll
        for (int reg = 0; reg < 4; ++reg) {
            int r = m0 + mw + i * 16 + fq * 4 + reg;
            if (r >= M) continue;
#pragma unroll
            for (int j = 0; j < 4; ++j)
                Cout[(size_t)r * N + n0 + nw + j * 16 + fm] = acc[i][j][reg] + bb[j];
        }
    }
}

// ---------------- fused EdgeConv (X-in-VGPR + pipelined W1-in-LDS) ----------------
// Block = 64 edges, 4 waves x 16 edges each. Per nc (8 x 64-hidden chunks):
//   [bar] 8x ds_write of PREFETCHED W1 slice regs; issue loads for nc+1 [bar]
//   stage1: H^T chunk = W1(LDS) x (own-edge X frags in VGPRs), K=256.
//           (b1 bias loads hoisted here so they land during the MFMAs)
//   exchange: +b1, relu, hi/lo split -> per-wave private LDS region;
//           within-wave only -> s_waitcnt lgkmcnt(0), no barrier.
//   stage2: macc += H chunk (LDS) x W2t rows (global, L2-hot), K=64.
// Epilogue: atomicMax(agg[edst], encf(macc)).
#define HST 72     // per-edge LDS h-stride in u16 (64 + 8 pad)
#define W1ST 264   // W1 slice LDS row stride in u16 (256 + 8 pad)

__global__ __launch_bounds__(256, 3) void k_edge_fused(const u16* __restrict__ Xh,
                                                       const u16* __restrict__ Xl,
                                                       const int* __restrict__ esrc,
                                                       const int* __restrict__ edst,
                                                       const u16* __restrict__ W1t,  // [512][256]
                                                       const float* __restrict__ b1, // [512]
                                                       const u16* __restrict__ W2t,  // [128][512]
                                                       u32* __restrict__ agg, int E) {
    __shared__ u16 W1s[64 * W1ST];     // 33792 B: current nc's W1 slice
    __shared__ u16 Hh[4 * 16 * HST];   // per-wave regions, hi plane (9216 B)
    __shared__ u16 Hl[4 * 16 * HST];   // lo plane
    const int tid = threadIdx.x;
    const int lane = tid & 63, wv = tid >> 6;
    const int fm = lane & 15, fq = lane >> 4;
    const int e0 = blockIdx.x * 64;

    // lane's owned edge (stage-1 B_op column fm)
    int eo = e0 + wv * 16 + fm;
    if (eo >= E) eo = E - 1;
    const size_t ndof = (size_t)edst[eo] * 128, nsof = (size_t)esrc[eo] * 128;

    // X fragments for the owned edge, loaded ONCE: k slice fq*8 of each 32-chunk
    bf16x8 xdh[4], xdl[4], xsh[4], xsl[4];
#pragma unroll
    for (int t = 0; t < 4; ++t) {
        int c = t * 32 + fq * 8;
        xdh[t] = *(const bf16x8*)(Xh + ndof + c);
        xdl[t] = *(const bf16x8*)(Xl + ndof + c);
        xsh[t] = *(const bf16x8*)(Xh + nsof + c);
        xsl[t] = *(const bf16x8*)(Xl + nsof + c);
    }

    // epilogue rows: macc row r holds edge e0 + wv*16 + fq*4 + r
    int erow[4];
#pragma unroll
    for (int r = 0; r < 4; ++r) {
        int e = e0 + wv * 16 + fq * 4 + r;
        erow[r] = (e < E) ? edst[e] : -1;
    }

    f32x4 macc[8];
#pragma unroll
    for (int of = 0; of < 8; ++of) { macc[of][0]=0.f; macc[of][1]=0.f; macc[of][2]=0.f; macc[of][3]=0.f; }

    // W1 staging map: thread copies 64 u16 of row tid>>2 at col (tid&3)*64
    const int s_row = tid >> 2, s_col = (tid & 3) * 64;
    const u16* w1g = W1t + (size_t)s_row * 256 + s_col;
    u16* w1l = &W1s[s_row * W1ST + s_col];

    // prologue: prefetch slice 0 into registers (T14 issue-early)
    uint4 pf[8];
#pragma unroll
    for (int j = 0; j < 8; ++j) pf[j] = *(const uint4*)(w1g + j * 8);

    const int lbase = (wv * 16 + fm) * HST;   // this lane's edge-row in H LDS

    for (int nc = 0; nc < 8; ++nc) {
        // ---- write prefetched W1 slice; issue loads for nc+1 ----
        __syncthreads();   // all waves done reading previous W1 slice
#pragma unroll
        for (int j = 0; j < 8; ++j) *(uint4*)(w1l + j * 8) = pf[j];
        if (nc < 7) {
            const u16* g = w1g + (size_t)(nc + 1) * 64 * 256;
#pragma unroll
            for (int j = 0; j < 8; ++j) pf[j] = *(const uint4*)(g + j * 8);
        }
        __syncthreads();   // W1 slice visible to all waves

        // hoisted bias loads: land during stage-1 MFMAs
        float4 bb4[4];
#pragma unroll
        for (int i = 0; i < 4; ++i)
            bb4[i] = *(const float4*)(b1 + nc * 64 + i * 16 + fq * 4);

        // ---- stage 1: H^T chunk, K=256; A_op = W1 rows (LDS), B_op = X regs ----
        f32x4 hacc[4];
#pragma unroll
        for (int i = 0; i < 4; ++i) { hacc[i][0]=0.f; hacc[i][1]=0.f; hacc[i][2]=0.f; hacc[i][3]=0.f; }

        const u16* w1p = &W1s[fm * W1ST + fq * 8];
#pragma unroll
        for (int t = 0; t < 8; ++t) {
            bf16x8 xh = (t < 4) ? xdh[t] : xsh[t - 4];
            bf16x8 xl = (t < 4) ? xdl[t] : xsl[t - 4];
#pragma unroll
            for (int i = 0; i < 4; ++i) {
                bf16x8 w1 = *(const bf16x8*)(w1p + i * 16 * W1ST + t * 32);
                hacc[i] = __builtin_amdgcn_mfma_f32_16x16x32_bf16(w1, xh, hacc[i], 0, 0, 0);
                hacc[i] = __builtin_amdgcn_mfma_f32_16x16x32_bf16(w1, xl, hacc[i], 0, 0, 0);
            }
        }

        // ---- exchange: +b1, relu, hi/lo split -> own wave's LDS region ----
        // WAR: previous nc's stage-2 ds_reads must complete before overwrite.
        asm volatile("s_waitcnt lgkmcnt(0)" ::: "memory");
#pragma unroll
        for (int i = 0; i < 4; ++i) {
            const float bv[4] = {bb4[i].x, bb4[i].y, bb4[i].z, bb4[i].w};
            u16 hi[4], lo[4];
#pragma unroll
            for (int r = 0; r < 4; ++r) {
                float h = hacc[i][r] + bv[r];
                h = h > 0.f ? h : 0.f;
                hi[r] = f2bf(h);
                lo[r] = f2bf(h - bf2f(hi[r]));
            }
            uint2 ph = {(u32)hi[0] | ((u32)hi[1] << 16), (u32)hi[2] | ((u32)hi[3] << 16)};
            uint2 pl = {(u32)lo[0] | ((u32)lo[1] << 16), (u32)lo[2] | ((u32)lo[3] << 16)};
            *(uint2*)&Hh[lbase + i * 16 + fq * 4] = ph;
            *(uint2*)&Hl[lbase + i * 16 + fq * 4] = pl;
        }
        // RAW: writes (all lanes of THIS wave) visible before reads.
        asm volatile("s_waitcnt lgkmcnt(0)" ::: "memory");

        // ---- stage 2: macc += H chunk @ W2[nc*64:+64, :], K = 64 ----
#pragma unroll
        for (int kk = 0; kk < 2; ++kk) {
            bf16x8 ah = *(const bf16x8*)&Hh[lbase + kk * 32 + fq * 8];
            bf16x8 al = *(const bf16x8*)&Hl[lbase + kk * 32 + fq * 8];
            const u16* w2p = W2t + (size_t)fm * 512 + nc * 64 + kk * 32 + fq * 8;
#pragma unroll
            for (int of = 0; of < 8; ++of) {
                bf16x8 w2 = *(const bf16x8*)(w2p + (size_t)of * 16 * 512);
                macc[of] = __builtin_amdgcn_mfma_f32_16x16x32_bf16(ah, w2, macc[of], 0, 0, 0);
                macc[of] = __builtin_amdgcn_mfma_f32_16x16x32_bf16(al, w2, macc[of], 0, 0, 0);
            }
        }
    }

    // ---- epilogue: scatter encoded atomicMax into agg[dst] ----
    // macc[of][r]: edge row = e0+wv*16+fq*4+r, out col = of*16+fm
#pragma unroll
    for (int r = 0; r < 4; ++r) {
        if (erow[r] < 0) continue;
        u32* base = agg + (size_t)erow[r] * 128 + fm;
#pragma unroll
        for (int of = 0; of < 8; ++of)
            atomicMax(base + of * 16, encf(macc[of][r]));
    }
}

// decode encoded-max buffer in place
__global__ __launch_bounds__(256) void k_decode(u32* __restrict__ agg,
                                                const float* __restrict__ b2,
                                                const float* __restrict__ gb, int n) {
    int i = blockIdx.x * 256 + threadIdx.x;
    if (i >= n) return;
    int c = i & 127;
    u32 u = agg[i];
    float v = (u == ENC_NEG_INF) ? 0.f : (decf(u) + b2[c]);
    if (gb) v += gb[c];
    ((float*)agg)[i] = v;
}

// ---------------- host side ----------------

extern "C" void kernel_launch(void* const* d_in, const int* in_sizes, int n_in,
                              void* d_out, int out_size, void* d_ws, size_t ws_size,
                              hipStream_t stream) {
    (void)in_sizes; (void)out_size;
    if (n_in < 26) return;
    if (ws_size < (size_t)240000000) return;

    const void* in_xl  = d_in[0];
    const void* in_xp  = d_in[1];
    const void* in_tWq = d_in[2];
    const void* in_tbq = d_in[3];
    const void* in_tWk = d_in[4];
    const void* in_tbk = d_in[5];
    const void* in_tWv = d_in[6];
    const void* in_tbv = d_in[7];
    const void* in_tWs = d_in[8];
    const void* in_tbs = d_in[9];
    const void* in_eW1 = d_in[10];
    const void* in_eb1 = d_in[11];
    const void* in_eW2 = d_in[12];
    const void* in_eb2 = d_in[13];
    const void* in_gW  = d_in[14];
    const void* in_gAs = d_in[15];
    const void* in_gAd = d_in[16];
    const void* in_gb  = d_in[17];
    const int* ll_src = (const int*)d_in[18];
    const int* ll_dst = (const int*)d_in[19];
    const int* pp_src = (const int*)d_in[20];
    const int* pp_dst = (const int*)d_in[21];
    const int* lp_src = (const int*)d_in[22];
    const int* lp_dst = (const int*)d_in[23];
    const int* pl_src = (const int*)d_in[24];
    const int* pl_dst = (const int*)d_in[25];

    // ---- workspace carve (~240.5 MB persistent) ----
    char* w = (char*)d_ws;
    auto alloc = [&](size_t bytes) -> char* {
        char* p = w;
        w += (bytes + 255) & ~(size_t)255;
        return p;
    };
    float* XL   = (float*)alloc((size_t)NL * 128 * 4);
    float* XP   = (float*)alloc((size_t)NP * 128 * 4);
    float* LA   = (float*)alloc((size_t)NL * 128 * 4);
    float* PA   = (float*)alloc((size_t)NP * 128 * 4);
    float* ssrc = (float*)alloc((size_t)NP * 4);
    float* sdst = (float*)alloc((size_t)NP * 4);
    float* wv2  = (float*)alloc(256 * 4);
    float* comb = (float*)alloc(128 * 4);
    u32*  dflag = (u32*)  alloc(256);
    float* tbqf = (float*)alloc(512 * 4);
    float* tbkf = (float*)alloc(512 * 4);
    float* tbvf = (float*)alloc(512 * 4);
    float* tbsf = (float*)alloc(512 * 4);
    float* eb1f = (float*)alloc(2048 * 4);
    float* eb2f = (float*)alloc(512 * 4);
    float* gWf  = (float*)alloc(65536 * 4);
    float* gAsf = (float*)alloc(512 * 4);
    float* gAdf = (float*)alloc(512 * 4);
    float* gbf  = (float*)alloc(512 * 4);
    // bf16 transposed weights [n][k]
    u16* tWqt = (u16*)alloc(65536 * 2);
    u16* tWkt = (u16*)alloc(65536 * 2);
    u16* tWvt = (u16*)alloc(65536 * 2);
    u16* tWst = (u16*)alloc(65536 * 2);
    u16* gWt  = (u16*)alloc(65536 * 2);
    u16* eW1t = (u16*)alloc(524288 * 2);
    u16* eW2t = (u16*)alloc(262144 * 2);
    // CSR (persistent): rowptr + col per attention graph
    int* rp_ll  = (int*)alloc((NL + 1) * 4);
    int* rp_lp  = (int*)alloc((NP + 1) * 4);
    int* rp_pl  = (int*)alloc((NL + 1) * 4);
    int* col_ll = (int*)alloc((size_t)ELL * 4);
    int* col_lp = (int*)alloc((size_t)ELPE * 4);
    int* col_pl = (int*)alloc((size_t)EPLE * 4);
    char* U = alloc(76800000);   // union region (76.8 MB)
    // U during prep: f32 weight staging, then CSR temps
    float* tWqf = (float*)U;
    float* tWkf = tWqf + 65536;
    float* tWvf = tWkf + 65536;
    float* tWsf = tWvf + 65536;
    float* eW1f = tWsf + 65536;
    float* eW2f = eW1f + 524288;
    // U during layers: trans_agg temps / GAT hs / edge-conv bf16 planes
    float* Tq  = (float*)U;
    float* Tk  = Tq + (size_t)NL * 128;
    float* Tv  = Tk + (size_t)NL * 128;
    float* Ghs = (float*)U;
    u16* Xph = (u16*)U;                    // [NP][128] hi plane (25.6 MB)
    u16* Xpl = Xph + (size_t)NP * 128;     // [NP][128] lo plane (25.6 MB)

    k_detect<<<1, 64, 0, stream>>>((const u32*)in_xl, dflag);

    auto cast = [&](const void* s_, float* d_, int n) {
        k_cast_any<<<(n + 255) / 256, 256, 0, stream>>>(s_, d_, n, dflag);
    };
    auto fillu = [&](void* p, u32 v, int n) {
        k_fill_u32<<<(n + 255) / 256, 256, 0, stream>>>((u32*)p, v, n);
    };
    auto tcast = [&](const float* s_, u16* d_, int K, int N, int nconv) {
        int total = nconv * K * N;
        k_tcast<<<(total + 255) / 256, 256, 0, stream>>>(s_, d_, K, N, total);
    };

    // ---- prep: casts + transposed bf16 weights (f32 temps in U) ----
    cast(in_xl, XL, NL * 128);
    cast(in_xp, XP, NP * 128);
    cast(in_tWq, tWqf, 65536); cast(in_tbq, tbqf, 512);
    cast(in_tWk, tWkf, 65536); cast(in_tbk, tbkf, 512);
    cast(in_tWv, tWvf, 65536); cast(in_tbv, tbvf, 512);
    cast(in_tWs, tWsf, 65536); cast(in_tbs, tbsf, 512);
    cast(in_eW1, eW1f, 524288); cast(in_eb1, eb1f, 2048);
    cast(in_eW2, eW2f, 262144); cast(in_eb2, eb2f, 512);
    cast(in_gW, gWf, 65536);
    cast(in_gAs, gAsf, 512); cast(in_gAd, gAdf, 512); cast(in_gb, gbf, 512);

    // fold "xj - xi" into W1 (rows 0..127 -= rows 128..255, per conv), then cast
    k_w1mod<<<(262144 + 255) / 256, 256, 0, stream>>>(eW1f, 262144);

    tcast(tWqf, tWqt, 128, 128, 4);
    tcast(tWkf, tWkt, 128, 128, 4);
    tcast(tWvf, tWvt, 128, 128, 4);
    tcast(tWsf, tWst, 128, 128, 4);
    tcast(gWf,  gWt,  128, 128, 4);
    tcast(eW1f, eW1t, 256, 512, 4);
    tcast(eW2f, eW2t, 512, 128, 4);

    // ---- CSR build (temps in U; weight temps are dead now) ----
    int* deg = (int*)U;
    int* cur = deg + NP + 64;
    int* aux = cur + NP + 64;
    auto build_csr = [&](const int* src, const int* dst, int E, int nd,
                         int* rp, int* col) {
        int nb = (nd + 255) / 256;
        fillu(deg, 0u, nd);
        k_deg<<<(E + 255) / 256, 256, 0, stream>>>(dst, deg, E);
        k_scan1<<<nb, 256, 0, stream>>>(deg, rp, aux, nd);
        k_scan2<<<1, 512, 0, stream>>>(aux, nb);
        k_scan3<<<(nd + 256) / 256, 256, 0, stream>>>(rp, aux, nd, E);
        k_copy_i32<<<(nd + 255) / 256, 256, 0, stream>>>(rp, cur, nd);
        k_scat<<<(E + 255) / 256, 256, 0, stream>>>(src, dst, cur, col, E);
    };
    build_csr(ll_src, ll_dst, ELL, NL, rp_ll, col_ll);
    build_csr(lp_src, lp_dst, ELPE, NP, rp_lp, col_lp);
    build_csr(pl_src, pl_dst, EPLE, NL, rp_pl, col_pl);

    // node-level MFMA GEMM launcher
    auto mgemm = [&](const float* A, const u16* Wt, const float* b, float* C,
                     int M, int N, int K) {
        dim3 g(N / 128, (M + 127) / 128);
        k_mgemm<<<g, 256, 0, stream>>>(A, Wt, b, C, M, N, K);
    };

    // ---- composite helpers ----
    auto trans_agg = [&](const float* Xin, float* out, int conv) {
        mgemm(Xin, tWqt + conv * 16384, tbqf + conv * 128, Tq, NL, 128, 128);
        mgemm(Xin, tWkt + conv * 16384, tbkf + conv * 128, Tk, NL, 128, 128);
        mgemm(Xin, tWvt + conv * 16384, tbvf + conv * 128, Tv, NL, 128, 128);
        k_attn_trans<<<(NL + 3) / 4, 256, 0, stream>>>(Tq, Tk, Tv, rp_ll, col_ll,
                                                       out, NL);
    };
    auto gat_conv = [&](const float* Xs, int ns, int nd,
                        const float* Xd, const int* rp, const int* col,
                        int g, float* out) {
        k_matvec2<<<2, 128, 0, stream>>>(gWf + g * 16384, gAsf + g * 128,
                                         gAdf + g * 128, wv2);
        k_node_scalar<<<(ns * 64 + 255) / 256, 256, 0, stream>>>(Xs, wv2, ssrc, ns);
        k_node_scalar<<<(nd * 64 + 255) / 256, 256, 0, stream>>>(Xd, wv2 + 128, sdst, nd);
        mgemm(Xs, gWt + g * 16384, nullptr, Ghs, ns, 128, 128);
        k_attn_gat<<<(nd + 3) / 4, 256, 0, stream>>>(Ghs, ssrc, sdst, rp, col,
                                                     out, nd);
    };
    // EdgeConv (point->point), fully fused; Xout (f32) = decoded max (+ optional gb)
    // Pre-splits Xin into bf16 hi/lo planes in U (Tq/Tk/Tv/Ghs dead by then).
    auto edge_conv = [&](const float* Xin, float* Xout, int conv, const float* gbext) {
        k_split<<<(NP * 32 + 255) / 256, 256, 0, stream>>>(
            (const float4*)Xin, (u16x4*)Xph, (u16x4*)Xpl, NP * 32);
        fillu(Xout, ENC_NEG_INF, NP * 128);
        k_edge_fused<<<(EPPE + 63) / 64, 256, 0, stream>>>(
            Xph, Xpl, pp_src, pp_dst,
            eW1t + conv * 131072, eb1f + conv * 512, eW2t + conv * 65536,
            (u32*)Xout, EPPE);
        k_decode<<<(NP * 128 + 255) / 256, 256, 0, stream>>>((u32*)Xout, eb2f + conv * 128,
                                                             gbext, NP * 128);
    };

    // ---- 2 layers ----
    for (int layer = 0; layer < 2; ++layer) {
        int cA = 2 * layer, cB = cA + 1;
        int g_lp = 2 * layer, g_pl = 2 * layer + 1;

        // conv A, lego side: LA = trans(XL) + gat_pl(XP->XL)
        k_add128<<<1, 128, 0, stream>>>(tbsf + cA * 128, gbf + g_pl * 128, comb);
        mgemm(XL, tWst + cA * 16384, comb, LA, NL, 128, 128);  // skip + both biases
        trans_agg(XL, LA, cA);
        gat_conv(XP, NP, NL, XL, rp_pl, col_pl, g_pl, LA);

        // conv A, point side: PA = edge_conv(XP) + gat_lp(XL->XP)
        edge_conv(XP, PA, cA, gbf + g_lp * 128);
        gat_conv(XL, NL, NP, XP, rp_lp, col_lp, g_lp, PA);

        // conv B: XL = trans(LA); XP = edge_conv(PA)
        mgemm(LA, tWst + cB * 16384, tbsf + cB * 128, XL, NL, 128, 128);
        trans_agg(LA, XL, cB);
        edge_conv(PA, XP, cB, nullptr);
    }

    // ---- emit output: [x_lego | x_point] ----
    k_store_out<<<(NL * 128 + 255) / 256, 256, 0, stream>>>(XL, d_out, 0, NL * 128, dflag);
    k_store_out<<<(NP * 128 + 255) / 256, 256, 0, stream>>>(XP, d_out, (size_t)NL * 128,
                                                            NP * 128, dflag);
}

// Round 7
// 4730.443 us; speedup vs baseline: 1.2229x; 1.2229x over previous
//
#include <hip/hip_runtime.h>

// GraphProcessor: 2-layer hetero GNN (TransformerConv + GATConv + EdgeConv)
// Round 15: revert r14's reg-prefetch (it spilled to scratch: WRITE_SIZE
//   200MB -> 1.7GB, dur 850 -> 1071). Back to r13's direct W1 staging, ONE
//   parameter change: 128 edges/block (8 waves, 512 threads). Same per-wave
//   code; each barrier fronts 2x MFMA work, W1 staging traffic halves,
//   16 waves/CU (was 12). LDS 70656B -> 2 blocks/CU.
//   Per-edge MFMA accumulation order unchanged -> bit-identical output
//   (absmax canary 0.265625).

typedef unsigned int u32;
typedef unsigned short u16;

#define NL 50000
#define NP 100000
#define ELL 500000
#define EPPE 400000
#define ELPE 500000
#define EPLE 500000
#define ENC_NEG_INF 0x007FFFFFu

using bf16x8 = __attribute__((ext_vector_type(8))) short;
using f32x4  = __attribute__((ext_vector_type(4))) float;
using u16x4  = __attribute__((ext_vector_type(4))) unsigned short;

__device__ __forceinline__ float bf2f(u16 h) { return __uint_as_float(((u32)h) << 16); }
__device__ __forceinline__ u16 f2bf(float f) {
    u32 u = __float_as_uint(f);
    u += 0x7FFFu + ((u >> 16) & 1u);   // round-to-nearest-even
    return (u16)(u >> 16);
}
// order-preserving float<->uint encoding (for atomicMax on floats)
__device__ __forceinline__ u32 encf(float f) {
    u32 u = __float_as_uint(f);
    return (u & 0x80000000u) ? ~u : (u | 0x80000000u);
}
__device__ __forceinline__ float decf(u32 u) {
    return __uint_as_float((u & 0x80000000u) ? (u ^ 0x80000000u) : ~u);
}

// ---------------- dtype detection ----------------
__global__ void k_detect(const u32* __restrict__ x, u32* __restrict__ flag) {
    int lane = threadIdx.x;   // 64 threads
    u16 lo = (u16)(x[lane] & 0xFFFFu);
    float a = fabsf(bf2f(lo));
    int inband = (a > 1e-4f && a < 100.f) ? 1 : 0;
    unsigned long long m = __ballot(inband);
    if (lane == 0) flag[0] = (__popcll(m) >= 32) ? 1u : 0u;   // 1 = bf16 inputs
}

// ---------------- elementwise / utility kernels ----------------

__global__ __launch_bounds__(256) void k_cast_any(const void* __restrict__ in,
                                                  float* __restrict__ out, int n,
                                                  const u32* __restrict__ flag) {
    int i = blockIdx.x * 256 + threadIdx.x;
    if (i >= n) return;
    if (flag[0]) out[i] = bf2f(((const u16*)in)[i]);
    else         out[i] = ((const float*)in)[i];
}

__global__ __launch_bounds__(256) void k_store_out(const float* __restrict__ in,
                                                   void* __restrict__ out, size_t off, int n,
                                                   const u32* __restrict__ flag) {
    int i = blockIdx.x * 256 + threadIdx.x;
    if (i >= n) return;
    if (flag[0]) ((u16*)out)[off + i] = f2bf(in[i]);
    else         ((float*)out)[off + i] = in[i];
}

__global__ __launch_bounds__(256) void k_fill_u32(u32* __restrict__ p, u32 v, int n) {
    int i = blockIdx.x * 256 + threadIdx.x;
    if (i < n) p[i] = v;
}

__global__ void k_add128(const float* __restrict__ a, const float* __restrict__ b,
                         float* __restrict__ o) {
    int t = threadIdx.x;
    o[t] = a[t] + b[t];
}

// transpose+cast: in = nconv blocks of [K][N] f32; out = nconv blocks of [N][K] bf16
__global__ __launch_bounds__(256) void k_tcast(const float* __restrict__ in,
                                               u16* __restrict__ out,
                                               int K, int N, int total) {
    int i = blockIdx.x * 256 + threadIdx.x;
    if (i >= total) return;
    int per = K * N;
    int c = i / per, r = i - c * per;
    int k = r / N, n = r - k * N;
    out[(size_t)c * per + (size_t)n * K + k] = f2bf(in[i]);
}

// fold EdgeConv's "xj - xi" into W1: rows 0..127 -= rows 128..255 (per conv)
__global__ __launch_bounds__(256) void k_w1mod(float* __restrict__ w, int total) {
    int i = blockIdx.x * 256 + threadIdx.x;   // total = 4 * 128 * 512
    if (i >= total) return;
    int c = i >> 16;              // / (128*512)
    int r = (i >> 9) & 127;
    int col = i & 511;
    float* base = w + c * 131072;
    base[r * 512 + col] -= base[(r + 128) * 512 + col];
}

// split f32 -> bf16 hi/lo planes (4 elems/thread)
__global__ __launch_bounds__(256) void k_split(const float4* __restrict__ x,
                                               u16x4* __restrict__ xh,
                                               u16x4* __restrict__ xl, int n4) {
    int i = blockIdx.x * 256 + threadIdx.x;
    if (i >= n4) return;
    float4 f = x[i];
    float fv[4] = {f.x, f.y, f.z, f.w};
    u16x4 h, l;
#pragma unroll
    for (int j = 0; j < 4; ++j) {
        u16 hi = f2bf(fv[j]);
        h[j] = hi;
        l[j] = f2bf(fv[j] - bf2f(hi));
    }
    xh[i] = h; xl[i] = l;
}

// o[b*128+k] = sum_i W[k*128+i] * a_b[i]  for b in {0,1}  (<<<2,128>>>)
__global__ void k_matvec2(const float* __restrict__ W, const float* __restrict__ a0,
                          const float* __restrict__ a1, float* __restrict__ o) {
    __shared__ float as[128];
    const float* a = blockIdx.x ? a1 : a0;
    int t = threadIdx.x;
    as[t] = a[t];
    __syncthreads();
    float s = 0.f;
#pragma unroll 8
    for (int i = 0; i < 128; ++i) s += W[t * 128 + i] * as[i];
    o[blockIdx.x * 128 + t] = s;
}

// s[n] = X[n,:] . wv   (one wave per node)
__global__ __launch_bounds__(256) void k_node_scalar(const float* __restrict__ X,
                                                     const float* __restrict__ wv,
                                                     float* __restrict__ s, int n) {
    int wid = (blockIdx.x * 256 + threadIdx.x) >> 6;
    int lane = threadIdx.x & 63;
    if (wid >= n) return;
    const float* xr = X + (size_t)wid * 128;
    float v = xr[lane] * wv[lane] + xr[lane + 64] * wv[lane + 64];
#pragma unroll
    for (int o = 32; o; o >>= 1) v += __shfl_xor(v, o);
    if (lane == 0) s[wid] = v;
}

// ---------------- CSR build: count -> scan -> scatter ----------------

__global__ __launch_bounds__(256) void k_deg(const int* __restrict__ dst,
                                             int* __restrict__ deg, int E) {
    int i = blockIdx.x * 256 + threadIdx.x;
    if (i < E) atomicAdd(deg + dst[i], 1);
}

__global__ __launch_bounds__(256) void k_scan1(const int* __restrict__ deg,
                                               int* __restrict__ rp,
                                               int* __restrict__ aux, int n) {
    __shared__ int ls[256];
    int t = threadIdx.x;
    int i = blockIdx.x * 256 + t;
    int v = (i < n) ? deg[i] : 0;
    ls[t] = v;
    __syncthreads();
#pragma unroll
    for (int off = 1; off < 256; off <<= 1) {
        int a = (t >= off) ? ls[t - off] : 0;
        __syncthreads();
        ls[t] += a;
        __syncthreads();
    }
    if (i < n) rp[i] = ls[t] - v;   // exclusive
    if (t == 255) aux[blockIdx.x] = ls[255];
}

__global__ __launch_bounds__(512) void k_scan2(int* __restrict__ aux, int nb) {
    __shared__ int ls[512];
    int t = threadIdx.x;
    int v = (t < nb) ? aux[t] : 0;
    ls[t] = v;
    __syncthreads();
#pragma unroll
    for (int off = 1; off < 512; off <<= 1) {
        int a = (t >= off) ? ls[t - off] : 0;
        __syncthreads();
        ls[t] += a;
        __syncthreads();
    }
    if (t < nb) aux[t] = ls[t] - v;   // exclusive
}

__global__ __launch_bounds__(256) void k_scan3(int* __restrict__ rp,
                                               const int* __restrict__ aux,
                                               int n, int E) {
    int i = blockIdx.x * 256 + threadIdx.x;
    if (i > n) return;
    if (i == n) rp[n] = E;
    else        rp[i] += aux[i >> 8];
}

__global__ __launch_bounds__(256) void k_copy_i32(const int* __restrict__ a,
                                                  int* __restrict__ b, int n) {
    int i = blockIdx.x * 256 + threadIdx.x;
    if (i < n) b[i] = a[i];
}

__global__ __launch_bounds__(256) void k_scat(const int* __restrict__ src,
                                              const int* __restrict__ dst,
                                              int* __restrict__ cur,
                                              int* __restrict__ col, int E) {
    int i = blockIdx.x * 256 + threadIdx.x;
    if (i >= E) return;
    int pos = atomicAdd(cur + dst[i], 1);
    col[pos] = src[i];
}

// ---------------- fused attention (one wave per dst row) ----------------

__global__ __launch_bounds__(256) void k_attn_trans(const float* __restrict__ Tq,
                                                    const float* __restrict__ Tk,
                                                    const float* __restrict__ Tv,
                                                    const int* __restrict__ rp,
                                                    const int* __restrict__ col,
                                                    float* __restrict__ out, int nd) {
    int row = (blockIdx.x * 256 + threadIdx.x) >> 6;
    int lane = threadIdx.x & 63;
    if (row >= nd) return;
    int e0 = rp[row], e1 = rp[row + 1];
    if (e0 >= e1) return;                      // no edges: out keeps skip
    const float* q = Tq + (size_t)row * 128;
    float q0 = q[lane], q1 = q[lane + 64];
    float m = -3.0e38f, l = 0.f, o0 = 0.f, o1 = 0.f;
    for (int e = e0; e < e1; ++e) {
        int s = col[e];
        const float* kr = Tk + (size_t)s * 128;
        float d = q0 * kr[lane] + q1 * kr[lane + 64];
#pragma unroll
        for (int off = 32; off; off >>= 1) d += __shfl_xor(d, off);
        d *= 0.08838834764831845f;             // 1/sqrt(128)
        float mn = fmaxf(m, d);
        float al = expf(m - mn);               // first iter: exp(-inf)=0
        float p  = expf(d - mn);
        const float* vr = Tv + (size_t)s * 128;
        l  = l * al + p;
        o0 = o0 * al + p * vr[lane];
        o1 = o1 * al + p * vr[lane + 64];
        m = mn;
    }
    float inv = 1.f / (l + 1e-16f);
    size_t base = (size_t)row * 128;
    out[base + lane]      += o0 * inv;
    out[base + lane + 64] += o1 * inv;
}

__global__ __launch_bounds__(256) void k_attn_gat(const float* __restrict__ hs,
                                                  const float* __restrict__ ss,
                                                  const float* __restrict__ sd,
                                                  const int* __restrict__ rp,
                                                  const int* __restrict__ col,
                                                  float* __restrict__ out, int nd) {
    int row = (blockIdx.x * 256 + threadIdx.x) >> 6;
    int lane = threadIdx.x & 63;
    if (row >= nd) return;
    int e0 = rp[row], e1 = rp[row + 1];
    if (e0 >= e1) return;
    float sdv = sd[row];
    float m = -3.0e38f, l = 0.f, o0 = 0.f, o1 = 0.f;
    for (int e = e0; e < e1; ++e) {
        int s = col[e];
        float sc = ss[s] + sdv;
        sc = sc > 0.f ? sc : 0.2f * sc;
        float mn = fmaxf(m, sc);
        float al = expf(m - mn);
        float p  = expf(sc - mn);
        const float* hr = hs + (size_t)s * 128;
        l  = l * al + p;
        o0 = o0 * al + p * hr[lane];
        o1 = o1 * al + p * hr[lane + 64];
        m = mn;
    }
    float inv = 1.f / (l + 1e-16f);
    size_t base = (size_t)row * 128;
    out[base + lane]      += o0 * inv;
    out[base + lane + 64] += o1 * inv;
}

// ---------------- MFMA GEMM (node-level): C = A[MxK] @ Wt^T + bias ----------------
// Wt bf16 [N][K]. A f32 staged as hi/lo bf16 planes (2-pass MFMA, ~f32 precision).
// Tile 128x128, BK=32, 4 waves (each 64x64 quadrant, 4x4 frags).
#define LSTR 40   // LDS row stride in bf16 (32 + 8 pad)

__global__ __launch_bounds__(256) void k_mgemm(const float* __restrict__ A_,
                                               const u16* __restrict__ Wt,
                                               const float* __restrict__ bias,
                                               float* __restrict__ Cout,
                                               int M, int N, int K) {
    __shared__ u16 Ahs[128 * LSTR];
    __shared__ u16 Als[128 * LSTR];
    __shared__ u16 Bss[128 * LSTR];
    const int tid = threadIdx.x;
    const int m0 = blockIdx.y * 128, n0 = blockIdx.x * 128;

    const int srow = tid >> 1, sseg = (tid & 1) * 16;
    int arow = m0 + srow;
    if (arow >= M) arow = M - 1;          // duplicate row; stores guarded
    const float* Af = A_ + (size_t)arow * K + sseg;
    u16* AhW = &Ahs[srow * LSTR + sseg];
    u16* AlW = &Als[srow * LSTR + sseg];
    const u16* Bp = Wt + (size_t)(n0 + srow) * K + sseg;
    u16* BsW = &Bss[srow * LSTR + sseg];

    const int lane = tid & 63, wv = tid >> 6;
    const int mw = (wv >> 1) * 64, nw = (wv & 1) * 64;
    const int fm = lane & 15, fq = lane >> 4;
    const u16* aRh = &Ahs[(mw + fm) * LSTR + fq * 8];
    const u16* aRl = &Als[(mw + fm) * LSTR + fq * 8];
    const u16* bR  = &Bss[(nw + fm) * LSTR + fq * 8];

    f32x4 acc[4][4];
#pragma unroll
    for (int i = 0; i < 4; ++i)
#pragma unroll
        for (int j = 0; j < 4; ++j) { acc[i][j][0]=0.f; acc[i][j][1]=0.f; acc[i][j][2]=0.f; acc[i][j][3]=0.f; }

    for (int k0 = 0; k0 < K; k0 += 32) {
        __syncthreads();
        float4 f0 = *(const float4*)(Af + k0);
        float4 f1 = *(const float4*)(Af + k0 + 4);
        float4 f2 = *(const float4*)(Af + k0 + 8);
        float4 f3 = *(const float4*)(Af + k0 + 12);
        float v[16] = {f0.x,f0.y,f0.z,f0.w, f1.x,f1.y,f1.z,f1.w,
                       f2.x,f2.y,f2.z,f2.w, f3.x,f3.y,f3.z,f3.w};
        u32 hp[8], lp[8];
#pragma unroll
        for (int i = 0; i < 8; ++i) {
            float x0 = v[2 * i], x1 = v[2 * i + 1];
            u16 h0 = f2bf(x0), h1 = f2bf(x1);
            u16 l0 = f2bf(x0 - bf2f(h0)), l1 = f2bf(x1 - bf2f(h1));
            hp[i] = (u32)h0 | ((u32)h1 << 16);
            lp[i] = (u32)l0 | ((u32)l1 << 16);
        }
        uint4 h04 = {hp[0], hp[1], hp[2], hp[3]}, h48 = {hp[4], hp[5], hp[6], hp[7]};
        uint4 l04 = {lp[0], lp[1], lp[2], lp[3]}, l48 = {lp[4], lp[5], lp[6], lp[7]};
        *(uint4*)AhW = h04; *(uint4*)(AhW + 8) = h48;
        *(uint4*)AlW = l04; *(uint4*)(AlW + 8) = l48;
        *(uint4*)BsW       = *(const uint4*)(Bp + k0);
        *(uint4*)(BsW + 8) = *(const uint4*)(Bp + k0 + 8);
        __syncthreads();

        bf16x8 ah[4], al[4], bfr[4];
#pragma unroll
        for (int i = 0; i < 4; ++i) ah[i]  = *(const bf16x8*)(aRh + i * 16 * LSTR);
#pragma unroll
        for (int i = 0; i < 4; ++i) al[i]  = *(const bf16x8*)(aRl + i * 16 * LSTR);
#pragma unroll
        for (int j = 0; j < 4; ++j) bfr[j] = *(const bf16x8*)(bR + j * 16 * LSTR);
#pragma unroll
        for (int i = 0; i < 4; ++i)
#pragma unroll
            for (int j = 0; j < 4; ++j) {
                acc[i][j] = __builtin_amdgcn_mfma_f32_16x16x32_bf16(ah[i], bfr[j],
                                                                    acc[i][j], 0, 0, 0);
                acc[i][j] = __builtin_amdgcn_mfma_f32_16x16x32_bf16(al[i], bfr[j],
                                                                    acc[i][j], 0, 0, 0);
            }
    }

    float bb[4];
#pragma unroll
    for (int j = 0; j < 4; ++j)
        bb[j] = bias ? bias[n0 + nw + j * 16 + fm] : 0.f;
#pragma unroll
    for (int i = 0; i < 4; ++i) {
#pragma unroll
        for (int reg = 0; reg < 4; ++reg) {
            int r = m0 + mw + i * 16 + fq * 4 + reg;
            if (r >= M) continue;
#pragma unroll
            for (int j = 0; j < 4; ++j)
                Cout[(size_t)r * N + n0 + nw + j * 16 + fm] = acc[i][j][reg] + bb[j];
        }
    }
}

// ---------------- fused EdgeConv (X-in-VGPR + W1-in-LDS, 128 edges/block) ----------------
// Block = 128 edges, 8 waves x 16 edges each. Per nc (8 x 64-hidden chunks):
//   [bar] cooperative stage of W1 slice (64 rows x 256 k, pad-264) [bar]
//   stage1: H^T chunk = W1(LDS) x (own-edge X frags in VGPRs), K=256.
//   exchange: +b1, relu, hi/lo split -> per-wave private LDS region;
//           within-wave only -> s_waitcnt lgkmcnt(0), no barrier.
//   stage2: macc += H chunk (LDS) x W2t rows (global, L2-hot), K=64.
// Epilogue: atomicMax(agg[edst], encf(macc)).
#define HST 72     // per-edge LDS h-stride in u16 (64 + 8 pad)
#define W1ST 264   // W1 slice LDS row stride in u16 (256 + 8 pad)

__global__ __launch_bounds__(512, 4) void k_edge_fused(const u16* __restrict__ Xh,
                                                       const u16* __restrict__ Xl,
                                                       const int* __restrict__ esrc,
                                                       const int* __restrict__ edst,
                                                       const u16* __restrict__ W1t,  // [512][256]
                                                       const float* __restrict__ b1, // [512]
                                                       const u16* __restrict__ W2t,  // [128][512]
                                                       u32* __restrict__ agg, int E) {
    __shared__ u16 W1s[64 * W1ST];     // 33792 B: current nc's W1 slice
    __shared__ u16 Hh[8 * 16 * HST];   // per-wave regions, hi plane (18432 B)
    __shared__ u16 Hl[8 * 16 * HST];   // lo plane
    const int tid = threadIdx.x;
    const int lane = tid & 63, wv = tid >> 6;   // wv 0..7
    const int fm = lane & 15, fq = lane >> 4;
    const int e0 = blockIdx.x * 128;

    // lane's owned edge (stage-1 B_op column fm)
    int eo = e0 + wv * 16 + fm;
    if (eo >= E) eo = E - 1;
    const size_t ndof = (size_t)edst[eo] * 128, nsof = (size_t)esrc[eo] * 128;

    // X fragments for the owned edge, loaded ONCE: k slice fq*8 of each 32-chunk
    bf16x8 xdh[4], xdl[4], xsh[4], xsl[4];
#pragma unroll
    for (int t = 0; t < 4; ++t) {
        int c = t * 32 + fq * 8;
        xdh[t] = *(const bf16x8*)(Xh + ndof + c);
        xdl[t] = *(const bf16x8*)(Xl + ndof + c);
        xsh[t] = *(const bf16x8*)(Xh + nsof + c);
        xsl[t] = *(const bf16x8*)(Xl + nsof + c);
    }

    // epilogue rows: macc row r holds edge e0 + wv*16 + fq*4 + r
    int erow[4];
#pragma unroll
    for (int r = 0; r < 4; ++r) {
        int e = e0 + wv * 16 + fq * 4 + r;
        erow[r] = (e < E) ? edst[e] : -1;
    }

    f32x4 macc[8];
#pragma unroll
    for (int of = 0; of < 8; ++of) { macc[of][0]=0.f; macc[of][1]=0.f; macc[of][2]=0.f; macc[of][3]=0.f; }

    // W1 staging map (512 threads): row tid>>3, col (tid&7)*32 (4x uint4 each)
    const int s_row = tid >> 3, s_col = (tid & 7) * 32;
    const u16* w1g = W1t + (size_t)s_row * 256 + s_col;
    u16* w1l = &W1s[s_row * W1ST + s_col];

    const int lbase = (wv * 16 + fm) * HST;   // this lane's edge-row in H LDS

    for (int nc = 0; nc < 8; ++nc) {
        // ---- cooperative W1 slice stage (rows nc*64 .. +64) ----
        __syncthreads();   // all waves done reading previous W1 slice
        {
            const u16* g = w1g + (size_t)nc * 64 * 256;
#pragma unroll
            for (int j = 0; j < 4; ++j)
                *(uint4*)(w1l + j * 8) = *(const uint4*)(g + j * 8);
        }
        __syncthreads();   // W1 slice visible to all waves

        // ---- stage 1: H^T chunk, K=256; A_op = W1 rows (LDS), B_op = X regs ----
        f32x4 hacc[4];
#pragma unroll
        for (int i = 0; i < 4; ++i) { hacc[i][0]=0.f; hacc[i][1]=0.f; hacc[i][2]=0.f; hacc[i][3]=0.f; }

        const u16* w1p = &W1s[fm * W1ST + fq * 8];
#pragma unroll
        for (int t = 0; t < 8; ++t) {
            bf16x8 xh = (t < 4) ? xdh[t] : xsh[t - 4];
            bf16x8 xl = (t < 4) ? xdl[t] : xsl[t - 4];
#pragma unroll
            for (int i = 0; i < 4; ++i) {
                bf16x8 w1 = *(const bf16x8*)(w1p + i * 16 * W1ST + t * 32);
                hacc[i] = __builtin_amdgcn_mfma_f32_16x16x32_bf16(w1, xh, hacc[i], 0, 0, 0);
                hacc[i] = __builtin_amdgcn_mfma_f32_16x16x32_bf16(w1, xl, hacc[i], 0, 0, 0);
            }
        }

        // ---- exchange: +b1, relu, hi/lo split -> own wave's LDS region ----
        // WAR: previous nc's stage-2 ds_reads must complete before overwrite.
        asm volatile("s_waitcnt lgkmcnt(0)" ::: "memory");
#pragma unroll
        for (int i = 0; i < 4; ++i) {
            float4 bb = *(const float4*)(b1 + nc * 64 + i * 16 + fq * 4);
            const float bv[4] = {bb.x, bb.y, bb.z, bb.w};
            u16 hi[4], lo[4];
#pragma unroll
            for (int r = 0; r < 4; ++r) {
                float h = hacc[i][r] + bv[r];
                h = h > 0.f ? h : 0.f;
                hi[r] = f2bf(h);
                lo[r] = f2bf(h - bf2f(hi[r]));
            }
            uint2 ph = {(u32)hi[0] | ((u32)hi[1] << 16), (u32)hi[2] | ((u32)hi[3] << 16)};
            uint2 pl = {(u32)lo[0] | ((u32)lo[1] << 16), (u32)lo[2] | ((u32)lo[3] << 16)};
            *(uint2*)&Hh[lbase + i * 16 + fq * 4] = ph;
            *(uint2*)&Hl[lbase + i * 16 + fq * 4] = pl;
        }
        // RAW: writes (all lanes of THIS wave) visible before reads.
        asm volatile("s_waitcnt lgkmcnt(0)" ::: "memory");

        // ---- stage 2: macc += H chunk @ W2[nc*64:+64, :], K = 64 ----
#pragma unroll
        for (int kk = 0; kk < 2; ++kk) {
            bf16x8 ah = *(const bf16x8*)&Hh[lbase + kk * 32 + fq * 8];
            bf16x8 al = *(const bf16x8*)&Hl[lbase + kk * 32 + fq * 8];
            const u16* w2p = W2t + (size_t)fm * 512 + nc * 64 + kk * 32 + fq * 8;
#pragma unroll
            for (int of = 0; of < 8; ++of) {
                bf16x8 w2 = *(const bf16x8*)(w2p + (size_t)of * 16 * 512);
                macc[of] = __builtin_amdgcn_mfma_f32_16x16x32_bf16(ah, w2, macc[of], 0, 0, 0);
                macc[of] = __builtin_amdgcn_mfma_f32_16x16x32_bf16(al, w2, macc[of], 0, 0, 0);
            }
        }
    }

    // ---- epilogue: scatter encoded atomicMax into agg[dst] ----
    // macc[of][r]: edge row = e0+wv*16+fq*4+r, out col = of*16+fm
#pragma unroll
    for (int r = 0; r < 4; ++r) {
        if (erow[r] < 0) continue;
        u32* base = agg + (size_t)erow[r] * 128 + fm;
#pragma unroll
        for (int of = 0; of < 8; ++of)
            atomicMax(base + of * 16, encf(macc[of][r]));
    }
}

// decode encoded-max buffer in place
__global__ __launch_bounds__(256) void k_decode(u32* __restrict__ agg,
                                                const float* __restrict__ b2,
                                                const float* __restrict__ gb, int n) {
    int i = blockIdx.x * 256 + threadIdx.x;
    if (i >= n) return;
    int c = i & 127;
    u32 u = agg[i];
    float v = (u == ENC_NEG_INF) ? 0.f : (decf(u) + b2[c]);
    if (gb) v += gb[c];
    ((float*)agg)[i] = v;
}

// ---------------- host side ----------------

extern "C" void kernel_launch(void* const* d_in, const int* in_sizes, int n_in,
                              void* d_out, int out_size, void* d_ws, size_t ws_size,
                              hipStream_t stream) {
    (void)in_sizes; (void)out_size;
    if (n_in < 26) return;
    if (ws_size < (size_t)240000000) return;

    const void* in_xl  = d_in[0];
    const void* in_xp  = d_in[1];
    const void* in_tWq = d_in[2];
    const void* in_tbq = d_in[3];
    const void* in_tWk = d_in[4];
    const void* in_tbk = d_in[5];
    const void* in_tWv = d_in[6];
    const void* in_tbv = d_in[7];
    const void* in_tWs = d_in[8];
    const void* in_tbs = d_in[9];
    const void* in_eW1 = d_in[10];
    const void* in_eb1 = d_in[11];
    const void* in_eW2 = d_in[12];
    const void* in_eb2 = d_in[13];
    const void* in_gW  = d_in[14];
    const void* in_gAs = d_in[15];
    const void* in_gAd = d_in[16];
    const void* in_gb  = d_in[17];
    const int* ll_src = (const int*)d_in[18];
    const int* ll_dst = (const int*)d_in[19];
    const int* pp_src = (const int*)d_in[20];
    const int* pp_dst = (const int*)d_in[21];
    const int* lp_src = (const int*)d_in[22];
    const int* lp_dst = (const int*)d_in[23];
    const int* pl_src = (const int*)d_in[24];
    const int* pl_dst = (const int*)d_in[25];

    // ---- workspace carve (~240.5 MB persistent) ----
    char* w = (char*)d_ws;
    auto alloc = [&](size_t bytes) -> char* {
        char* p = w;
        w += (bytes + 255) & ~(size_t)255;
        return p;
    };
    float* XL   = (float*)alloc((size_t)NL * 128 * 4);
    float* XP   = (float*)alloc((size_t)NP * 128 * 4);
    float* LA   = (float*)alloc((size_t)NL * 128 * 4);
    float* PA   = (float*)alloc((size_t)NP * 128 * 4);
    float* ssrc = (float*)alloc((size_t)NP * 4);
    float* sdst = (float*)alloc((size_t)NP * 4);
    float* wv2  = (float*)alloc(256 * 4);
    float* comb = (float*)alloc(128 * 4);
    u32*  dflag = (u32*)  alloc(256);
    float* tbqf = (float*)alloc(512 * 4);
    float* tbkf = (float*)alloc(512 * 4);
    float* tbvf = (float*)alloc(512 * 4);
    float* tbsf = (float*)alloc(512 * 4);
    float* eb1f = (float*)alloc(2048 * 4);
    float* eb2f = (float*)alloc(512 * 4);
    float* gWf  = (float*)alloc(65536 * 4);
    float* gAsf = (float*)alloc(512 * 4);
    float* gAdf = (float*)alloc(512 * 4);
    float* gbf  = (float*)alloc(512 * 4);
    // bf16 transposed weights [n][k]
    u16* tWqt = (u16*)alloc(65536 * 2);
    u16* tWkt = (u16*)alloc(65536 * 2);
    u16* tWvt = (u16*)alloc(65536 * 2);
    u16* tWst = (u16*)alloc(65536 * 2);
    u16* gWt  = (u16*)alloc(65536 * 2);
    u16* eW1t = (u16*)alloc(524288 * 2);
    u16* eW2t = (u16*)alloc(262144 * 2);
    // CSR (persistent): rowptr + col per attention graph
    int* rp_ll  = (int*)alloc((NL + 1) * 4);
    int* rp_lp  = (int*)alloc((NP + 1) * 4);
    int* rp_pl  = (int*)alloc((NL + 1) * 4);
    int* col_ll = (int*)alloc((size_t)ELL * 4);
    int* col_lp = (int*)alloc((size_t)ELPE * 4);
    int* col_pl = (int*)alloc((size_t)EPLE * 4);
    char* U = alloc(76800000);   // union region (76.8 MB)
    // U during prep: f32 weight staging, then CSR temps
    float* tWqf = (float*)U;
    float* tWkf = tWqf + 65536;
    float* tWvf = tWkf + 65536;
    float* tWsf = tWvf + 65536;
    float* eW1f = tWsf + 65536;
    float* eW2f = eW1f + 524288;
    // U during layers: trans_agg temps / GAT hs / edge-conv bf16 planes
    float* Tq  = (float*)U;
    float* Tk  = Tq + (size_t)NL * 128;
    float* Tv  = Tk + (size_t)NL * 128;
    float* Ghs = (float*)U;
    u16* Xph = (u16*)U;                    // [NP][128] hi plane (25.6 MB)
    u16* Xpl = Xph + (size_t)NP * 128;     // [NP][128] lo plane (25.6 MB)

    k_detect<<<1, 64, 0, stream>>>((const u32*)in_xl, dflag);

    auto cast = [&](const void* s_, float* d_, int n) {
        k_cast_any<<<(n + 255) / 256, 256, 0, stream>>>(s_, d_, n, dflag);
    };
    auto fillu = [&](void* p, u32 v, int n) {
        k_fill_u32<<<(n + 255) / 256, 256, 0, stream>>>((u32*)p, v, n);
    };
    auto tcast = [&](const float* s_, u16* d_, int K, int N, int nconv) {
        int total = nconv * K * N;
        k_tcast<<<(total + 255) / 256, 256, 0, stream>>>(s_, d_, K, N, total);
    };

    // ---- prep: casts + transposed bf16 weights (f32 temps in U) ----
    cast(in_xl, XL, NL * 128);
    cast(in_xp, XP, NP * 128);
    cast(in_tWq, tWqf, 65536); cast(in_tbq, tbqf, 512);
    cast(in_tWk, tWkf, 65536); cast(in_tbk, tbkf, 512);
    cast(in_tWv, tWvf, 65536); cast(in_tbv, tbvf, 512);
    cast(in_tWs, tWsf, 65536); cast(in_tbs, tbsf, 512);
    cast(in_eW1, eW1f, 524288); cast(in_eb1, eb1f, 2048);
    cast(in_eW2, eW2f, 262144); cast(in_eb2, eb2f, 512);
    cast(in_gW, gWf, 65536);
    cast(in_gAs, gAsf, 512); cast(in_gAd, gAdf, 512); cast(in_gb, gbf, 512);

    // fold "xj - xi" into W1 (rows 0..127 -= rows 128..255, per conv), then cast
    k_w1mod<<<(262144 + 255) / 256, 256, 0, stream>>>(eW1f, 262144);

    tcast(tWqf, tWqt, 128, 128, 4);
    tcast(tWkf, tWkt, 128, 128, 4);
    tcast(tWvf, tWvt, 128, 128, 4);
    tcast(tWsf, tWst, 128, 128, 4);
    tcast(gWf,  gWt,  128, 128, 4);
    tcast(eW1f, eW1t, 256, 512, 4);
    tcast(eW2f, eW2t, 512, 128, 4);

    // ---- CSR build (temps in U; weight temps are dead now) ----
    int* deg = (int*)U;
    int* cur = deg + NP + 64;
    int* aux = cur + NP + 64;
    auto build_csr = [&](const int* src, const int* dst, int E, int nd,
                         int* rp, int* col) {
        int nb = (nd + 255) / 256;
        fillu(deg, 0u, nd);
        k_deg<<<(E + 255) / 256, 256, 0, stream>>>(dst, deg, E);
        k_scan1<<<nb, 256, 0, stream>>>(deg, rp, aux, nd);
        k_scan2<<<1, 512, 0, stream>>>(aux, nb);
        k_scan3<<<(nd + 256) / 256, 256, 0, stream>>>(rp, aux, nd, E);
        k_copy_i32<<<(nd + 255) / 256, 256, 0, stream>>>(rp, cur, nd);
        k_scat<<<(E + 255) / 256, 256, 0, stream>>>(src, dst, cur, col, E);
    };
    build_csr(ll_src, ll_dst, ELL, NL, rp_ll, col_ll);
    build_csr(lp_src, lp_dst, ELPE, NP, rp_lp, col_lp);
    build_csr(pl_src, pl_dst, EPLE, NL, rp_pl, col_pl);

    // node-level MFMA GEMM launcher
    auto mgemm = [&](const float* A, const u16* Wt, const float* b, float* C,
                     int M, int N, int K) {
        dim3 g(N / 128, (M + 127) / 128);
        k_mgemm<<<g, 256, 0, stream>>>(A, Wt, b, C, M, N, K);
    };

    // ---- composite helpers ----
    auto trans_agg = [&](const float* Xin, float* out, int conv) {
        mgemm(Xin, tWqt + conv * 16384, tbqf + conv * 128, Tq, NL, 128, 128);
        mgemm(Xin, tWkt + conv * 16384, tbkf + conv * 128, Tk, NL, 128, 128);
        mgemm(Xin, tWvt + conv * 16384, tbvf + conv * 128, Tv, NL, 128, 128);
        k_attn_trans<<<(NL + 3) / 4, 256, 0, stream>>>(Tq, Tk, Tv, rp_ll, col_ll,
                                                       out, NL);
    };
    auto gat_conv = [&](const float* Xs, int ns, int nd,
                        const float* Xd, const int* rp, const int* col,
                        int g, float* out) {
        k_matvec2<<<2, 128, 0, stream>>>(gWf + g * 16384, gAsf + g * 128,
                                         gAdf + g * 128, wv2);
        k_node_scalar<<<(ns * 64 + 255) / 256, 256, 0, stream>>>(Xs, wv2, ssrc, ns);
        k_node_scalar<<<(nd * 64 + 255) / 256, 256, 0, stream>>>(Xd, wv2 + 128, sdst, nd);
        mgemm(Xs, gWt + g * 16384, nullptr, Ghs, ns, 128, 128);
        k_attn_gat<<<(nd + 3) / 4, 256, 0, stream>>>(Ghs, ssrc, sdst, rp, col,
                                                     out, nd);
    };
    // EdgeConv (point->point), fully fused; Xout (f32) = decoded max (+ optional gb)
    // Pre-splits Xin into bf16 hi/lo planes in U (Tq/Tk/Tv/Ghs dead by then).
    auto edge_conv = [&](const float* Xin, float* Xout, int conv, const float* gbext) {
        k_split<<<(NP * 32 + 255) / 256, 256, 0, stream>>>(
            (const float4*)Xin, (u16x4*)Xph, (u16x4*)Xpl, NP * 32);
        fillu(Xout, ENC_NEG_INF, NP * 128);
        k_edge_fused<<<(EPPE + 127) / 128, 512, 0, stream>>>(
            Xph, Xpl, pp_src, pp_dst,
            eW1t + conv * 131072, eb1f + conv * 512, eW2t + conv * 65536,
            (u32*)Xout, EPPE);
        k_decode<<<(NP * 128 + 255) / 256, 256, 0, stream>>>((u32*)Xout, eb2f + conv * 128,
                                                             gbext, NP * 128);
    };

    // ---- 2 layers ----
    for (int layer = 0; layer < 2; ++layer) {
        int cA = 2 * layer, cB = cA + 1;
        int g_lp = 2 * layer, g_pl = 2 * layer + 1;

        // conv A, lego side: LA = trans(XL) + gat_pl(XP->XL)
        k_add128<<<1, 128, 0, stream>>>(tbsf + cA * 128, gbf + g_pl * 128, comb);
        mgemm(XL, tWst + cA * 16384, comb, LA, NL, 128, 128);  // skip + both biases
        trans_agg(XL, LA, cA);
        gat_conv(XP, NP, NL, XL, rp_pl, col_pl, g_pl, LA);

        // conv A, point side: PA = edge_conv(XP) + gat_lp(XL->XP)
        edge_conv(XP, PA, cA, gbf + g_lp * 128);
        gat_conv(XL, NL, NP, XP, rp_lp, col_lp, g_lp, PA);

        // conv B: XL = trans(LA); XP = edge_conv(PA)
        mgemm(LA, tWst + cB * 16384, tbsf + cB * 128, XL, NL, 128, 128);
        trans_agg(LA, XL, cB);
        edge_conv(PA, XP, cB, nullptr);
    }

    // ---- emit output: [x_lego | x_point] ----
    k_store_out<<<(NL * 128 + 255) / 256, 256, 0, stream>>>(XL, d_out, 0, NL * 128, dflag);
    k_store_out<<<(NP * 128 + 255) / 256, 256, 0, stream>>>(XP, d_out, (size_t)NL * 128,
                                                            NP * 128, dflag);
}